// Round 6
// baseline (724.456 us; speedup 1.0000x reference)
//
#include <hip/hip_runtime.h>
#include <math.h>

#define NROWS (512 * 512)   // B*T = 262144
#define KCB   1024          // codebook size
#define DDIM  64            // embedding dim
#define TKP   128           // k-range per tile pass (even half staged in LDS)
#define RPT   2             // rows per thread (hr=128 regs; RPT=4 spills — R3)
#define BLK   128           // threads per block
#define NQ    ((size_t)NROWS * DDIM)

// B_k = sum_i weight[k][i]^2, fp32, numpy pairwise-8 pattern
__global__ void wsq_kernel(const float* __restrict__ w, float* __restrict__ bsq) {
    int k = blockIdx.x * blockDim.x + threadIdx.x;
    if (k >= KCB) return;
    const float* row = w + (size_t)k * DDIM;
    float r[8];
#pragma unroll
    for (int j = 0; j < 8; ++j) r[j] = __fmul_rn(row[j], row[j]);
#pragma unroll
    for (int i = 8; i < DDIM; i += 8)
#pragma unroll
        for (int j = 0; j < 8; ++j)
            r[j] = __fadd_rn(r[j], __fmul_rn(row[i + j], row[i + j]));
    bsq[k] = __fadd_rn(__fadd_rn(__fadd_rn(r[0], r[1]), __fadd_rn(r[2], r[3])),
                       __fadd_rn(__fadd_rn(r[4], r[5]), __fadd_rn(r[6], r[7])));
}

// Split w-feed: even-k rows via LDS broadcast (lgkmcnt pipe),
// odd-k rows via wave-uniform global_load through L1 (vmcnt pipe).
// VALU FMA chain is then the binding resource.
__global__ __launch_bounds__(BLK, 2)
void vq_main(const float* __restrict__ h, const float* __restrict__ w,
             const float* __restrict__ bsq, float* __restrict__ out) {
    __shared__ float wl[(TKP / 2) * DDIM];   // 16 KB: even-k rows of current tile

    const int tid = threadIdx.x;
    const size_t rowbase = (size_t)blockIdx.x * (BLK * RPT) + (size_t)tid * RPT;

    // opaque per-lane zero: defeats uniformity analysis so odd-k loads stay VMEM
    int vzero;
    asm volatile("v_mov_b32 %0, 0" : "=v"(vzero));

    // 2 h rows -> registers
    float hr[RPT][DDIM];
#pragma unroll
    for (int r = 0; r < RPT; ++r) {
        const float* hrow = h + (rowbase + r) * DDIM;
#pragma unroll
        for (int i = 0; i < DDIM; i += 4) {
            float4 v = *reinterpret_cast<const float4*>(hrow + i);
            hr[r][i] = v.x; hr[r][i + 1] = v.y; hr[r][i + 2] = v.z; hr[r][i + 3] = v.w;
        }
    }

    // A_r = (h**2).sum per row, numpy pairwise-8 ordering (frozen — validated R2)
    float A[RPT];
#pragma unroll
    for (int r = 0; r < RPT; ++r) {
        float s[8];
#pragma unroll
        for (int j = 0; j < 8; ++j) s[j] = __fmul_rn(hr[r][j], hr[r][j]);
#pragma unroll
        for (int i = 8; i < DDIM; i += 8)
#pragma unroll
            for (int j = 0; j < 8; ++j)
                s[j] = __fadd_rn(s[j], __fmul_rn(hr[r][i + j], hr[r][i + j]));
        A[r] = __fadd_rn(__fadd_rn(__fadd_rn(s[0], s[1]), __fadd_rn(s[2], s[3])),
                         __fadd_rn(__fadd_rn(s[4], s[5]), __fadd_rn(s[6], s[7])));
    }

    float best[RPT];
    int bestk[RPT];
#pragma unroll
    for (int r = 0; r < RPT; ++r) { best[r] = INFINITY; bestk[r] = 0; }

#pragma unroll 1
    for (int t0 = 0; t0 < KCB; t0 += TKP) {
        __syncthreads();
        // stage even-k rows (64 rows x 256B) coalesced: 1024 float4 / 128 threads
        const float4* wsrc4 = reinterpret_cast<const float4*>(w + (size_t)t0 * DDIM);
        float4* wdst4 = reinterpret_cast<float4*>(wl);
#pragma unroll
        for (int j = 0; j < 8; ++j) {
            int idx = j * BLK + tid;          // 0..1023
            int r2i = idx >> 4;               // even-row ordinal 0..63
            int c   = idx & 15;               // float4 column
            wdst4[idx] = wsrc4[((size_t)r2i << 5) + c];   // src row = 2*r2i
        }
        __syncthreads();

#pragma unroll 1
        for (int kq = 0; kq < TKP; kq += 2) {
            const float* w0p = wl + (kq >> 1) * DDIM;                    // even k: LDS broadcast
            const float* w1g = w + ((size_t)(t0 + kq + 1)) * DDIM + vzero; // odd k: global/L1 (VMEM)
            float a[RPT][2];
#pragma unroll
            for (int r = 0; r < RPT; ++r) { a[r][0] = 0.f; a[r][1] = 0.f; }
#pragma unroll
            for (int i = 0; i < DDIM; i += 4) {
                float4 x0 = *reinterpret_cast<const float4*>(w0p + i);
                float4 x1 = *reinterpret_cast<const float4*>(w1g + i);
#pragma unroll
                for (int r = 0; r < RPT; ++r) {
                    // k-ascending single-accumulator chains, ascending d (frozen order)
                    a[r][0] = fmaf(hr[r][i + 0], x0.x, a[r][0]);
                    a[r][0] = fmaf(hr[r][i + 1], x0.y, a[r][0]);
                    a[r][0] = fmaf(hr[r][i + 2], x0.z, a[r][0]);
                    a[r][0] = fmaf(hr[r][i + 3], x0.w, a[r][0]);
                    a[r][1] = fmaf(hr[r][i + 0], x1.x, a[r][1]);
                    a[r][1] = fmaf(hr[r][i + 1], x1.y, a[r][1]);
                    a[r][1] = fmaf(hr[r][i + 2], x1.z, a[r][1]);
                    a[r][1] = fmaf(hr[r][i + 3], x1.w, a[r][1]);
                }
            }
            float b0 = bsq[t0 + kq];        // uniform -> scalar pipe (4 KB, K$-resident)
            float b1 = bsq[t0 + kq + 1];
#pragma unroll
            for (int r = 0; r < RPT; ++r) {
                float d0 = __fsub_rn(__fadd_rn(A[r], b0), __fadd_rn(a[r][0], a[r][0]));
                float d1 = __fsub_rn(__fadd_rn(A[r], b1), __fadd_rn(a[r][1], a[r][1]));
                if (d0 < best[r]) { best[r] = d0; bestk[r] = t0 + kq + 0; }
                if (d1 < best[r]) { best[r] = d1; bestk[r] = t0 + kq + 1; }
            }
        }
    }

    // ---- epilogue (all f32): qst = h + (q - h); loss; idx ---- (frozen — validated R2)
#pragma unroll
    for (int r = 0; r < RPT; ++r) {
        const size_t n = rowbase + r;
        const float* qrow = w + (size_t)bestk[r] * DDIM;
        float* qst = out + n * DDIM;
        float r2[8];
#pragma unroll
        for (int c = 0; c < 8; ++c) {
            float4 qa = *reinterpret_cast<const float4*>(qrow + 8 * c);
            float4 qb = *reinterpret_cast<const float4*>(qrow + 8 * c + 4);
            float d0 = __fsub_rn(qa.x, hr[r][8 * c + 0]);
            float d1 = __fsub_rn(qa.y, hr[r][8 * c + 1]);
            float d2 = __fsub_rn(qa.z, hr[r][8 * c + 2]);
            float d3 = __fsub_rn(qa.w, hr[r][8 * c + 3]);
            float d4 = __fsub_rn(qb.x, hr[r][8 * c + 4]);
            float d5 = __fsub_rn(qb.y, hr[r][8 * c + 5]);
            float d6 = __fsub_rn(qb.z, hr[r][8 * c + 6]);
            float d7 = __fsub_rn(qb.w, hr[r][8 * c + 7]);
            if (c == 0) {
                r2[0] = __fmul_rn(d0, d0); r2[1] = __fmul_rn(d1, d1);
                r2[2] = __fmul_rn(d2, d2); r2[3] = __fmul_rn(d3, d3);
                r2[4] = __fmul_rn(d4, d4); r2[5] = __fmul_rn(d5, d5);
                r2[6] = __fmul_rn(d6, d6); r2[7] = __fmul_rn(d7, d7);
            } else {
                r2[0] = __fadd_rn(r2[0], __fmul_rn(d0, d0));
                r2[1] = __fadd_rn(r2[1], __fmul_rn(d1, d1));
                r2[2] = __fadd_rn(r2[2], __fmul_rn(d2, d2));
                r2[3] = __fadd_rn(r2[3], __fmul_rn(d3, d3));
                r2[4] = __fadd_rn(r2[4], __fmul_rn(d4, d4));
                r2[5] = __fadd_rn(r2[5], __fmul_rn(d5, d5));
                r2[6] = __fadd_rn(r2[6], __fmul_rn(d6, d6));
                r2[7] = __fadd_rn(r2[7], __fmul_rn(d7, d7));
            }
            float4 oa, ob;
            oa.x = __fadd_rn(hr[r][8 * c + 0], d0);
            oa.y = __fadd_rn(hr[r][8 * c + 1], d1);
            oa.z = __fadd_rn(hr[r][8 * c + 2], d2);
            oa.w = __fadd_rn(hr[r][8 * c + 3], d3);
            ob.x = __fadd_rn(hr[r][8 * c + 4], d4);
            ob.y = __fadd_rn(hr[r][8 * c + 5], d5);
            ob.z = __fadd_rn(hr[r][8 * c + 6], d6);
            ob.w = __fadd_rn(hr[r][8 * c + 7], d7);
            *reinterpret_cast<float4*>(qst + 8 * c) = oa;
            *reinterpret_cast<float4*>(qst + 8 * c + 4) = ob;
        }
        float S = __fadd_rn(__fadd_rn(__fadd_rn(r2[0], r2[1]), __fadd_rn(r2[2], r2[3])),
                            __fadd_rn(__fadd_rn(r2[4], r2[5]), __fadd_rn(r2[6], r2[7])));
        float m = __fmul_rn(S, 0.015625f);
        float loss = __fadd_rn(__fmul_rn(m, 0.1f), __fmul_rn(m, 0.2f));
        out[NQ + n] = (float)bestk[r];
        out[NQ + NROWS + n] = loss;
    }
}

extern "C" void kernel_launch(void* const* d_in, const int* in_sizes, int n_in,
                              void* d_out, int out_size, void* d_ws, size_t ws_size,
                              hipStream_t stream) {
    (void)in_sizes; (void)n_in; (void)out_size; (void)ws_size;
    const float* h = (const float*)d_in[0];
    const float* w = (const float*)d_in[1];
    float* bsq = (float*)d_ws;
    float* out = (float*)d_out;

    wsq_kernel<<<(KCB + 255) / 256, 256, 0, stream>>>(w, bsq);
    vq_main<<<NROWS / (BLK * RPT), BLK, 0, stream>>>(h, w, bsq, out);
}

// Round 8
// 552.795 us; speedup vs baseline: 1.3105x; 1.3105x over previous
//
#include <hip/hip_runtime.h>
#include <math.h>

#define NROWS (512 * 512)   // B*T = 262144
#define KCB   1024          // codebook size
#define DDIM  64            // embedding dim
#define TKP   128           // k-range per tile pass (even half staged in LDS)
#define RPT   2             // rows per thread (hr=128 regs; RPT=4 spills — R3)
#define BLK   256           // threads per block
#define NQ    ((size_t)NROWS * DDIM)

// B_k = sum_i weight[k][i]^2, fp32, numpy pairwise-8 pattern (frozen — validated R2)
__global__ void wsq_kernel(const float* __restrict__ w, float* __restrict__ bsq) {
    int k = blockIdx.x * blockDim.x + threadIdx.x;
    if (k >= KCB) return;
    const float* row = w + (size_t)k * DDIM;
    float r[8];
#pragma unroll
    for (int j = 0; j < 8; ++j) r[j] = __fmul_rn(row[j], row[j]);
#pragma unroll
    for (int i = 8; i < DDIM; i += 8)
#pragma unroll
        for (int j = 0; j < 8; ++j)
            r[j] = __fadd_rn(r[j], __fmul_rn(row[i + j], row[i + j]));
    bsq[k] = __fadd_rn(__fadd_rn(__fadd_rn(r[0], r[1]), __fadd_rn(r[2], r[3])),
                       __fadd_rn(__fadd_rn(r[4], r[5]), __fadd_rn(r[6], r[7])));
}

// Split w-feed with explicit software pipelining:
//   even-k rows: LDS broadcast (uniform ds_read_b128, inline loads)
//   odd-k rows:  wave-uniform global loads, HALF-ROW (32-float) in-place
//                rotating buffers oddA (d0-31) / oddB (d32-63), prefetched
//                one pair ahead (~380 cyc load-to-use).
__global__ __launch_bounds__(BLK, 2)
void vq_main(const float* __restrict__ h, const float* __restrict__ w,
             const float* __restrict__ bsq, float* __restrict__ out) {
    __shared__ float wl[(TKP / 2) * DDIM];   // 16 KB: even-k rows of current tile

    const int tid = threadIdx.x;
    const size_t rowbase = (size_t)blockIdx.x * (BLK * RPT) + (size_t)tid * RPT;

    // opaque per-lane zero: keeps odd-k loads on the VMEM pipe (R4 scalarization trap)
    int vzero;
    asm volatile("v_mov_b32 %0, 0" : "=v"(vzero));

    // 2 h rows -> registers (128)
    float hr[RPT][DDIM];
#pragma unroll
    for (int r = 0; r < RPT; ++r) {
        const float* hrow = h + (rowbase + r) * DDIM;
#pragma unroll
        for (int i = 0; i < DDIM; i += 4) {
            float4 v = *reinterpret_cast<const float4*>(hrow + i);
            hr[r][i] = v.x; hr[r][i + 1] = v.y; hr[r][i + 2] = v.z; hr[r][i + 3] = v.w;
        }
    }

    // A_r = (h**2).sum per row, numpy pairwise-8 ordering (frozen — validated R2)
    float A[RPT];
#pragma unroll
    for (int r = 0; r < RPT; ++r) {
        float s[8];
#pragma unroll
        for (int j = 0; j < 8; ++j) s[j] = __fmul_rn(hr[r][j], hr[r][j]);
#pragma unroll
        for (int i = 8; i < DDIM; i += 8)
#pragma unroll
            for (int j = 0; j < 8; ++j)
                s[j] = __fadd_rn(s[j], __fmul_rn(hr[r][i + j], hr[r][i + j]));
        A[r] = __fadd_rn(__fadd_rn(__fadd_rn(s[0], s[1]), __fadd_rn(s[2], s[3])),
                         __fadd_rn(__fadd_rn(s[4], s[5]), __fadd_rn(s[6], s[7])));
    }

    float best[RPT];
    int bestk[RPT];
#pragma unroll
    for (int r = 0; r < RPT; ++r) { best[r] = INFINITY; bestk[r] = 0; }

    // prologue: odd row k=1, both halves (8+8 float4 = 64 regs)
    float4 oddA[8], oddB[8];
    {
        const float* wg = w + (size_t)DDIM + vzero;   // row 1
#pragma unroll
        for (int j = 0; j < 8; ++j)
            oddA[j] = *reinterpret_cast<const float4*>(wg + 4 * j);        // d0..31
#pragma unroll
        for (int j = 0; j < 8; ++j)
            oddB[j] = *reinterpret_cast<const float4*>(wg + 32 + 4 * j);   // d32..63
    }

#pragma unroll 1
    for (int t0 = 0; t0 < KCB; t0 += TKP) {
        __syncthreads();
        // stage even-k rows (64 rows x 256 B): 1024 float4 / 256 threads
        const float4* wsrc4 = reinterpret_cast<const float4*>(w + (size_t)t0 * DDIM);
        float4* wdst4 = reinterpret_cast<float4*>(wl);
#pragma unroll
        for (int j = 0; j < 4; ++j) {
            int idx = j * BLK + tid;          // 0..1023
            int r2i = idx >> 4;               // even-row ordinal 0..63
            int c   = idx & 15;               // float4 column
            wdst4[idx] = wsrc4[((size_t)r2i << 5) + c];   // src row = 2*r2i
        }
        __syncthreads();

#pragma unroll 1
        for (int kq = 0; kq < TKP; kq += 2) {
            const int ke = t0 + kq;                       // even k; odd k = ke+1
            const float* wep = wl + (kq >> 1) * DDIM;     // even row in LDS
            int kn = ke + 3;                              // next pair's odd row
            if (kn > KCB - 1) kn = KCB - 1;               // tail clamp (dup load, unused)
            const float* wgn = w + (size_t)kn * DDIM + vzero;

            float ao[RPT], ae[RPT];
#pragma unroll
            for (int r = 0; r < RPT; ++r) { ao[r] = 0.f; ae[r] = 0.f; }

            // (b) odd chain part1: d0..31 from oddA (i-ascending, single acc)
#pragma unroll
            for (int j = 0; j < 8; ++j)
#pragma unroll
                for (int r = 0; r < RPT; ++r) {
                    ao[r] = fmaf(hr[r][4 * j + 0], oddA[j].x, ao[r]);
                    ao[r] = fmaf(hr[r][4 * j + 1], oddA[j].y, ao[r]);
                    ao[r] = fmaf(hr[r][4 * j + 2], oddA[j].z, ao[r]);
                    ao[r] = fmaf(hr[r][4 * j + 3], oddA[j].w, ao[r]);
                }
            // (c) reissue oddA <- row kn, d0..31 (consumed next pair)
#pragma unroll
            for (int j = 0; j < 8; ++j)
                oddA[j] = *reinterpret_cast<const float4*>(wgn + 4 * j);

            // (d) even chain part1: d0..31 from LDS (inline uniform b128)
#pragma unroll
            for (int j = 0; j < 8; ++j) {
                float4 x = *reinterpret_cast<const float4*>(wep + 4 * j);
#pragma unroll
                for (int r = 0; r < RPT; ++r) {
                    ae[r] = fmaf(hr[r][4 * j + 0], x.x, ae[r]);
                    ae[r] = fmaf(hr[r][4 * j + 1], x.y, ae[r]);
                    ae[r] = fmaf(hr[r][4 * j + 2], x.z, ae[r]);
                    ae[r] = fmaf(hr[r][4 * j + 3], x.w, ae[r]);
                }
            }

            // (f) odd chain part2: d32..63 from oddB (same acc — full i-ascending chain)
#pragma unroll
            for (int j = 0; j < 8; ++j)
#pragma unroll
                for (int r = 0; r < RPT; ++r) {
                    ao[r] = fmaf(hr[r][32 + 4 * j + 0], oddB[j].x, ao[r]);
                    ao[r] = fmaf(hr[r][32 + 4 * j + 1], oddB[j].y, ao[r]);
                    ao[r] = fmaf(hr[r][32 + 4 * j + 2], oddB[j].z, ao[r]);
                    ao[r] = fmaf(hr[r][32 + 4 * j + 3], oddB[j].w, ao[r]);
                }
            // (g) reissue oddB <- row kn, d32..63
#pragma unroll
            for (int j = 0; j < 8; ++j)
                oddB[j] = *reinterpret_cast<const float4*>(wgn + 32 + 4 * j);

            // (h) even chain part2: d32..63 from LDS
#pragma unroll
            for (int j = 0; j < 8; ++j) {
                float4 x = *reinterpret_cast<const float4*>(wep + 32 + 4 * j);
#pragma unroll
                for (int r = 0; r < RPT; ++r) {
                    ae[r] = fmaf(hr[r][32 + 4 * j + 0], x.x, ae[r]);
                    ae[r] = fmaf(hr[r][32 + 4 * j + 1], x.y, ae[r]);
                    ae[r] = fmaf(hr[r][32 + 4 * j + 2], x.z, ae[r]);
                    ae[r] = fmaf(hr[r][32 + 4 * j + 3], x.w, ae[r]);
                }
            }

            // (i) dist + k-ascending first-min-wins (even k=ke first, then ke+1)
            float b0 = bsq[ke], b1 = bsq[ke + 1];   // scalar pipe (4 KB, K$-resident)
#pragma unroll
            for (int r = 0; r < RPT; ++r) {
                float de = __fsub_rn(__fadd_rn(A[r], b0), __fadd_rn(ae[r], ae[r]));
                float dd = __fsub_rn(__fadd_rn(A[r], b1), __fadd_rn(ao[r], ao[r]));
                if (de < best[r]) { best[r] = de; bestk[r] = ke; }
                if (dd < best[r]) { best[r] = dd; bestk[r] = ke + 1; }
            }
        }
    }

    // ---- epilogue (all f32): qst = h + (q - h); loss; idx ---- (frozen — validated R2)
#pragma unroll
    for (int r = 0; r < RPT; ++r) {
        const size_t n = rowbase + r;
        const float* qrow = w + (size_t)bestk[r] * DDIM;
        float* qst = out + n * DDIM;
        float r2[8];
#pragma unroll
        for (int c = 0; c < 8; ++c) {
            float4 qa = *reinterpret_cast<const float4*>(qrow + 8 * c);
            float4 qb = *reinterpret_cast<const float4*>(qrow + 8 * c + 4);
            float d0 = __fsub_rn(qa.x, hr[r][8 * c + 0]);
            float d1 = __fsub_rn(qa.y, hr[r][8 * c + 1]);
            float d2 = __fsub_rn(qa.z, hr[r][8 * c + 2]);
            float d3 = __fsub_rn(qa.w, hr[r][8 * c + 3]);
            float d4 = __fsub_rn(qb.x, hr[r][8 * c + 4]);
            float d5 = __fsub_rn(qb.y, hr[r][8 * c + 5]);
            float d6 = __fsub_rn(qb.z, hr[r][8 * c + 6]);
            float d7 = __fsub_rn(qb.w, hr[r][8 * c + 7]);
            if (c == 0) {
                r2[0] = __fmul_rn(d0, d0); r2[1] = __fmul_rn(d1, d1);
                r2[2] = __fmul_rn(d2, d2); r2[3] = __fmul_rn(d3, d3);
                r2[4] = __fmul_rn(d4, d4); r2[5] = __fmul_rn(d5, d5);
                r2[6] = __fmul_rn(d6, d6); r2[7] = __fmul_rn(d7, d7);
            } else {
                r2[0] = __fadd_rn(r2[0], __fmul_rn(d0, d0));
                r2[1] = __fadd_rn(r2[1], __fmul_rn(d1, d1));
                r2[2] = __fadd_rn(r2[2], __fmul_rn(d2, d2));
                r2[3] = __fadd_rn(r2[3], __fmul_rn(d3, d3));
                r2[4] = __fadd_rn(r2[4], __fmul_rn(d4, d4));
                r2[5] = __fadd_rn(r2[5], __fmul_rn(d5, d5));
                r2[6] = __fadd_rn(r2[6], __fmul_rn(d6, d6));
                r2[7] = __fadd_rn(r2[7], __fmul_rn(d7, d7));
            }
            float4 oa, ob;
            oa.x = __fadd_rn(hr[r][8 * c + 0], d0);
            oa.y = __fadd_rn(hr[r][8 * c + 1], d1);
            oa.z = __fadd_rn(hr[r][8 * c + 2], d2);
            oa.w = __fadd_rn(hr[r][8 * c + 3], d3);
            ob.x = __fadd_rn(hr[r][8 * c + 4], d4);
            ob.y = __fadd_rn(hr[r][8 * c + 5], d5);
            ob.z = __fadd_rn(hr[r][8 * c + 6], d6);
            ob.w = __fadd_rn(hr[r][8 * c + 7], d7);
            *reinterpret_cast<float4*>(qst + 8 * c) = oa;
            *reinterpret_cast<float4*>(qst + 8 * c + 4) = ob;
        }
        float S = __fadd_rn(__fadd_rn(__fadd_rn(r2[0], r2[1]), __fadd_rn(r2[2], r2[3])),
                            __fadd_rn(__fadd_rn(r2[4], r2[5]), __fadd_rn(r2[6], r2[7])));
        float m = __fmul_rn(S, 0.015625f);
        float loss = __fadd_rn(__fmul_rn(m, 0.1f), __fmul_rn(m, 0.2f));
        out[NQ + n] = (float)bestk[r];
        out[NQ + NROWS + n] = loss;
    }
}

extern "C" void kernel_launch(void* const* d_in, const int* in_sizes, int n_in,
                              void* d_out, int out_size, void* d_ws, size_t ws_size,
                              hipStream_t stream) {
    (void)in_sizes; (void)n_in; (void)out_size; (void)ws_size;
    const float* h = (const float*)d_in[0];
    const float* w = (const float*)d_in[1];
    float* bsq = (float*)d_ws;
    float* out = (float*)d_out;

    wsq_kernel<<<(KCB + 255) / 256, 256, 0, stream>>>(w, bsq);
    vq_main<<<NROWS / (BLK * RPT), BLK, 0, stream>>>(h, w, bsq, out);
}